// Round 1
// baseline (12222.260 us; speedup 1.0000x reference)
//
#include <hip/hip_runtime.h>
#include <math.h>

namespace {

constexpr int kB  = 256;   // batch
constexpr int kT  = 512;   // timesteps
constexpr int kIn = 128;   // layer0 input size
constexpr int kH  = 256;   // hidden
constexpr int kG  = 1024;  // 4*H
constexpr int kNC = 100;   // classes
constexpr int kCT = 64;    // timestep chunk
constexpr int kNCh = kT / kCT;
constexpr int kBT = 4;     // batch rows per recurrence block

__device__ __forceinline__ float sigm(float x) { return 1.0f / (1.0f + __expf(-x)); }
__device__ __forceinline__ float tanh_f(float x) { return 2.0f / (1.0f + __expf(-2.0f * x)) - 1.0f; }

// Pack W_hh [4H][H] (row-major, gates i,f,g,o stacked) into Wp where
// Wp[(k*kH + j)] (as float4) = { W_i[j][k], W_f[j][k], W_g[j][k], W_o[j][k] }.
__global__ void pack_whh(const float* __restrict__ whh, float* __restrict__ wp) {
  const int idx = blockIdx.x * blockDim.x + threadIdx.x;  // k*256 + j
  const int j = idx & (kH - 1);
  const int k = idx >> 8;
  float4 w;
  w.x = whh[(0 * kH + j) * kH + k];
  w.y = whh[(1 * kH + j) * kH + k];
  w.z = whh[(2 * kH + j) * kH + k];
  w.w = whh[(3 * kH + j) * kH + k];
  reinterpret_cast<float4*>(wp)[idx] = w;
}

// P[m][n] = sum_k X[xrow(m)][k] * W[n][k] + b1[n] + b2[n]
// xrow(m) = (m / kCT) * xT + t0 + (m % kCT)   (maps chunk row -> source row)
// 64x64 tile, BK=16, 256 threads, 4x4 strided micro-tile.
template <int K>
__global__ __launch_bounds__(256) void gemm_xw(
    const float* __restrict__ X, const float* __restrict__ W,
    const float* __restrict__ b1, const float* __restrict__ b2,
    float* __restrict__ P, int t0, int xT) {
  __shared__ float sA[64][20];  // row-stride 20 floats: <=2-way (free) bank aliasing
  __shared__ float sB[64][20];
  const int tid = threadIdx.x;
  const int tx = tid & 15;
  const int ty = tid >> 4;
  const int lm = tid >> 2;         // 0..63 staging row
  const int lk = (tid & 3) << 2;   // 0,4,8,12 staging k-quad
  const int mt = blockIdx.y;
  const int nt = blockIdx.x;

  const int m_g = mt * 64 + lm;
  const int xrow = (m_g >> 6) * xT + t0 + (m_g & 63);
  const float* Arow = X + (size_t)xrow * K;
  const float* Brow = W + (size_t)(nt * 64 + lm) * K;

  float acc[4][4] = {};
  for (int kt = 0; kt < K; kt += 16) {
    const float4 av = *reinterpret_cast<const float4*>(Arow + kt + lk);
    const float4 bv = *reinterpret_cast<const float4*>(Brow + kt + lk);
    __syncthreads();
    *reinterpret_cast<float4*>(&sA[lm][lk]) = av;
    *reinterpret_cast<float4*>(&sB[lm][lk]) = bv;
    __syncthreads();
#pragma unroll
    for (int kq = 0; kq < 4; ++kq) {
      float4 a4[4], b4[4];
#pragma unroll
      for (int i = 0; i < 4; ++i)
        a4[i] = *reinterpret_cast<const float4*>(&sA[ty + 16 * i][kq * 4]);
#pragma unroll
      for (int j = 0; j < 4; ++j)
        b4[j] = *reinterpret_cast<const float4*>(&sB[tx + 16 * j][kq * 4]);
#pragma unroll
      for (int i = 0; i < 4; ++i)
#pragma unroll
        for (int j = 0; j < 4; ++j) {
          acc[i][j] += a4[i].x * b4[j].x;
          acc[i][j] += a4[i].y * b4[j].y;
          acc[i][j] += a4[i].z * b4[j].z;
          acc[i][j] += a4[i].w * b4[j].w;
        }
    }
  }
#pragma unroll
  for (int j = 0; j < 4; ++j) {
    const int n = nt * 64 + tx + 16 * j;
    const float bb = b1[n] + b2[n];
#pragma unroll
    for (int i = 0; i < 4; ++i) {
      const int m = mt * 64 + ty + 16 * i;
      P[(size_t)m * kG + n] = acc[i][j] + bb;
    }
  }
}

// LSTM recurrence over one chunk of kCT steps. Grid = kB/kBT blocks x 256 thr.
// Thread j owns hidden unit j for kBT batch rows. h lives in LDS (gate-shared),
// c lives in registers. No cross-block communication needed (batch-parallel).
__global__ __launch_bounds__(256) void lstm_rec(
    const float* __restrict__ P,    // [kB*kCT][kG], m = b*kCT + tt
    const float* __restrict__ Wp,   // packed [kH*kH] float4 (see pack_whh)
    float* __restrict__ hstate,     // [kB][kH]
    float* __restrict__ cstate,     // [kB][kH]
    float* __restrict__ Hout,       // [kB*kCT][kH] or nullptr
    int first) {
  const int j = threadIdx.x;
  const int b0 = blockIdx.x * kBT;
  __shared__ float4 sh4[kH];  // sh4[k] = h[k] for batch rows b0..b0+3

  float c0, c1, c2, c3;
  float4 hv;
  if (first) {
    hv = make_float4(0.f, 0.f, 0.f, 0.f);
    c0 = c1 = c2 = c3 = 0.f;
  } else {
    hv.x = hstate[(b0 + 0) * kH + j];
    hv.y = hstate[(b0 + 1) * kH + j];
    hv.z = hstate[(b0 + 2) * kH + j];
    hv.w = hstate[(b0 + 3) * kH + j];
    c0 = cstate[(b0 + 0) * kH + j];
    c1 = cstate[(b0 + 1) * kH + j];
    c2 = cstate[(b0 + 2) * kH + j];
    c3 = cstate[(b0 + 3) * kH + j];
  }
  sh4[j] = hv;
  __syncthreads();

  const float4* wp4 = reinterpret_cast<const float4*>(Wp);
  for (int tt = 0; tt < kCT; ++tt) {
    float a0[kBT], a1[kBT], a2[kBT], a3[kBT];
#pragma unroll
    for (int r = 0; r < kBT; ++r) {
      const float* p = P + ((size_t)(b0 + r) * kCT + tt) * kG;
      a0[r] = p[j];
      a1[r] = p[kH + j];
      a2[r] = p[2 * kH + j];
      a3[r] = p[3 * kH + j];
    }
#pragma unroll 8
    for (int k = 0; k < kH; ++k) {
      const float4 w = wp4[k * kH + j];   // coalesced dwordx4, L2-resident
      const float4 h4 = sh4[k];           // broadcast ds_read_b128
      a0[0] += w.x * h4.x; a0[1] += w.x * h4.y; a0[2] += w.x * h4.z; a0[3] += w.x * h4.w;
      a1[0] += w.y * h4.x; a1[1] += w.y * h4.y; a1[2] += w.y * h4.z; a1[3] += w.y * h4.w;
      a2[0] += w.z * h4.x; a2[1] += w.z * h4.y; a2[2] += w.z * h4.z; a2[3] += w.z * h4.w;
      a3[0] += w.w * h4.x; a3[1] += w.w * h4.y; a3[2] += w.w * h4.z; a3[3] += w.w * h4.w;
    }
    __syncthreads();  // all reads of old h done
    float nh0, nh1, nh2, nh3;
    {
      float ig, fg, gg, og;
      ig = sigm(a0[0]); fg = sigm(a1[0]); gg = tanh_f(a2[0]); og = sigm(a3[0]);
      c0 = fg * c0 + ig * gg; nh0 = og * tanh_f(c0);
      ig = sigm(a0[1]); fg = sigm(a1[1]); gg = tanh_f(a2[1]); og = sigm(a3[1]);
      c1 = fg * c1 + ig * gg; nh1 = og * tanh_f(c1);
      ig = sigm(a0[2]); fg = sigm(a1[2]); gg = tanh_f(a2[2]); og = sigm(a3[2]);
      c2 = fg * c2 + ig * gg; nh2 = og * tanh_f(c2);
      ig = sigm(a0[3]); fg = sigm(a1[3]); gg = tanh_f(a2[3]); og = sigm(a3[3]);
      c3 = fg * c3 + ig * gg; nh3 = og * tanh_f(c3);
    }
    sh4[j] = make_float4(nh0, nh1, nh2, nh3);
    if (Hout) {
      Hout[((size_t)(b0 + 0) * kCT + tt) * kH + j] = nh0;
      Hout[((size_t)(b0 + 1) * kCT + tt) * kH + j] = nh1;
      Hout[((size_t)(b0 + 2) * kCT + tt) * kH + j] = nh2;
      Hout[((size_t)(b0 + 3) * kCT + tt) * kH + j] = nh3;
    }
    __syncthreads();  // new h visible before next step's reads
  }
  hv = sh4[j];
  hstate[(b0 + 0) * kH + j] = hv.x;
  hstate[(b0 + 1) * kH + j] = hv.y;
  hstate[(b0 + 2) * kH + j] = hv.z;
  hstate[(b0 + 3) * kH + j] = hv.w;
  cstate[(b0 + 0) * kH + j] = c0;
  cstate[(b0 + 1) * kH + j] = c1;
  cstate[(b0 + 2) * kH + j] = c2;
  cstate[(b0 + 3) * kH + j] = c3;
}

// out[b][n] = sum_k hlast[b][k] * fcw[n][k] + fcb[n]
__global__ __launch_bounds__(128) void fc_kernel(
    const float* __restrict__ hlast, const float* __restrict__ fcw,
    const float* __restrict__ fcb, float* __restrict__ out) {
  const int b = blockIdx.x;
  const int n = threadIdx.x;
  __shared__ float sh[kH];
  sh[n] = hlast[b * kH + n];
  sh[n + 128] = hlast[b * kH + n + 128];
  __syncthreads();
  if (n < kNC) {
    float a = fcb[n];
    const float* wrow = fcw + n * kH;
#pragma unroll 8
    for (int k = 0; k < kH; ++k) a += sh[k] * wrow[k];
    out[b * kNC + n] = a;
  }
}

}  // namespace

extern "C" void kernel_launch(void* const* d_in, const int* in_sizes, int n_in,
                              void* d_out, int out_size, void* d_ws, size_t ws_size,
                              hipStream_t stream) {
  (void)in_sizes; (void)n_in; (void)out_size; (void)ws_size;
  const float* x    = (const float*)d_in[0];
  const float* Wih0 = (const float*)d_in[1];
  const float* Whh0 = (const float*)d_in[2];
  const float* bih0 = (const float*)d_in[3];
  const float* bhh0 = (const float*)d_in[4];
  const float* Wih1 = (const float*)d_in[5];
  const float* Whh1 = (const float*)d_in[6];
  const float* bih1 = (const float*)d_in[7];
  const float* bhh1 = (const float*)d_in[8];
  const float* fcw  = (const float*)d_in[9];
  const float* fcb  = (const float*)d_in[10];
  float* out = (float*)d_out;

  // Workspace layout (~147 MB total)
  char* base = (char*)d_ws;
  const size_t szP = (size_t)kB * kCT * kG * sizeof(float);  // 64 MB
  const size_t szH = (size_t)kB * kCT * kH * sizeof(float);  // 16 MB
  const size_t szS = (size_t)kB * kH * sizeof(float);        // 256 KB
  const size_t szW = (size_t)kH * kH * 4 * sizeof(float);    // 1 MB
  float* P0  = (float*)(base);
  float* P1  = (float*)(base + szP);
  float* H0  = (float*)(base + 2 * szP);
  float* h0s = (float*)(base + 2 * szP + szH);
  float* c0s = (float*)(base + 2 * szP + szH + 1 * szS);
  float* h1s = (float*)(base + 2 * szP + szH + 2 * szS);
  float* c1s = (float*)(base + 2 * szP + szH + 3 * szS);
  float* Wp0 = (float*)(base + 2 * szP + szH + 4 * szS);
  float* Wp1 = (float*)(base + 2 * szP + szH + 4 * szS + szW);

  pack_whh<<<dim3(kH * kH / 256), dim3(256), 0, stream>>>(Whh0, Wp0);
  pack_whh<<<dim3(kH * kH / 256), dim3(256), 0, stream>>>(Whh1, Wp1);

  const dim3 ggrid(kG / 64, kB * kCT / 64);  // (16, 256)
  for (int ch = 0; ch < kNCh; ++ch) {
    gemm_xw<kIn><<<ggrid, dim3(256), 0, stream>>>(x, Wih0, bih0, bhh0, P0,
                                                  ch * kCT, kT);
    lstm_rec<<<dim3(kB / kBT), dim3(256), 0, stream>>>(P0, Wp0, h0s, c0s, H0,
                                                       ch == 0 ? 1 : 0);
    gemm_xw<kH><<<ggrid, dim3(256), 0, stream>>>(H0, Wih1, bih1, bhh1, P1,
                                                 0, kCT);
    lstm_rec<<<dim3(kB / kBT), dim3(256), 0, stream>>>(P1, Wp1, h1s, c1s,
                                                       nullptr, ch == 0 ? 1 : 0);
  }
  fc_kernel<<<dim3(kB), dim3(128), 0, stream>>>(h1s, fcw, fcb, out);
}

// Round 2
// 8425.197 us; speedup vs baseline: 1.4507x; 1.4507x over previous
//
#include <hip/hip_runtime.h>
#include <math.h>

namespace {

constexpr int kB  = 256;   // batch
constexpr int kT  = 512;   // timesteps
constexpr int kIn = 128;   // layer0 input size
constexpr int kH  = 256;   // hidden
constexpr int kG  = 1024;  // 4*H
constexpr int kNC = 100;   // classes
constexpr int kCT = 64;    // timestep chunk
constexpr int kNCh = kT / kCT;

typedef __bf16 bf16x8 __attribute__((ext_vector_type(8)));
typedef float f32x4 __attribute__((ext_vector_type(4)));
static_assert(sizeof(bf16x8) == 16, "bf16x8 must be 4 VGPRs");

__device__ __forceinline__ float sigm(float x) { return 1.0f / (1.0f + __expf(-x)); }
__device__ __forceinline__ float tanh_f(float x) { return 2.0f / (1.0f + __expf(-2.0f * x)) - 1.0f; }
__device__ __forceinline__ unsigned short f2bf(float f) {
  return __builtin_bit_cast(unsigned short, (__bf16)f);
}

// ---------------------------------------------------------------------------
// Pack W_hh [4H][H] fp32 into bf16 MFMA B-fragment order.
// Fragment (wave wv, gate g, k-block kb): lane l, elem e holds
//   B[k][n] = Whh[n][k],  n = g*256 + wv*16 + (l&15),  k = kb*32 + ((l>>4)&3)*8 + e
// Flat layout: wpk[(((wv*4+g)*8+kb)*64 + l)*8 + e]
__global__ __launch_bounds__(256) void pack_whh_frag(
    const float* __restrict__ whh, unsigned short* __restrict__ wpk) {
  const int idx = blockIdx.x * 256 + threadIdx.x;   // 0..262143
  const int e  = idx & 7;
  const int l  = (idx >> 3) & 63;
  const int kb = (idx >> 9) & 7;
  const int g  = (idx >> 12) & 3;
  const int wv = idx >> 14;
  const int n = (g << 8) | (wv << 4) | (l & 15);
  const int k = (kb << 5) | (((l >> 4) & 3) << 3) | e;
  wpk[idx] = f2bf(whh[n * kH + k]);
}

// ---------------------------------------------------------------------------
// MFMA LSTM recurrence over one chunk of kCT steps.
// Grid: kB/16 = 16 blocks. Block: 1024 threads = 16 waves.
// Block owns batch rows [b0, b0+16). Wave wv owns hidden units [wv*16, wv*16+16)
// and computes all 4 gates for them -> activation is in-lane, c in registers.
// h (bf16) double-buffered in LDS in exact A-fragment order (conflict-free
// ds_read_b128). P (fp32) prefetched one step ahead, used as MFMA C-operand.
__global__ __launch_bounds__(1024) void lstm_rec_mfma(
    const float* __restrict__ P,            // [kB*kCT][kG], row = b*kCT + tt
    const unsigned short* __restrict__ wpk, // packed bf16 B-fragments
    float* __restrict__ hstate,             // [kB][kH]
    float* __restrict__ cstate,             // [kB][kH]
    float* __restrict__ Hout,               // [kB*kCT][kH] or nullptr
    int first) {
  const int tid = threadIdx.x;
  const int wv = tid >> 6;
  const int l  = tid & 63;
  const int b0 = blockIdx.x << 4;
  const int jj = (wv << 4) | (l & 15);   // hidden unit owned (as D column)
  const int mg = (l >> 4) << 2;          // base batch row of this lane's D rows

  __shared__ __align__(16) unsigned short abuf[2][8 * 512];  // 2 x 8KB, frag order

  // Persistent B fragments: 4 gates x 8 k-blocks, 128 VGPRs.
  bf16x8 bfr[4][8];
  {
    const unsigned short* wbase = wpk + (size_t)wv * 32 * 512;
#pragma unroll
    for (int g = 0; g < 4; ++g)
#pragma unroll
      for (int kb = 0; kb < 8; ++kb)
        bfr[g][kb] = *reinterpret_cast<const bf16x8*>(wbase + ((g * 8 + kb) * 64 + l) * 8);
  }

  // Load / init state. Lane owns (rows mg..mg+3, unit jj).
  f32x4 c4;
  float hnew[4];
  if (first) {
#pragma unroll
    for (int r = 0; r < 4; ++r) { c4[r] = 0.f; hnew[r] = 0.f; }
  } else {
#pragma unroll
    for (int r = 0; r < 4; ++r) {
      hnew[r] = hstate[(b0 + mg + r) * kH + jj];
      c4[r]   = cstate[(b0 + mg + r) * kH + jj];
    }
  }
  {
    const int kb_w = jj >> 5, hi = (jj >> 3) & 3, e = jj & 7;
#pragma unroll
    for (int r = 0; r < 4; ++r)
      abuf[0][kb_w * 512 + ((mg + r) | (hi << 4)) * 8 + e] = f2bf(hnew[r]);
  }
  __syncthreads();

  // P base for this lane: row (b0+mg), column jj; +g*256 selects gate.
  const float* Pb = P + ((size_t)(b0 + mg) * kCT) * kG + jj;

  // Prefetch P for step 0.
  f32x4 pfr[4];
#pragma unroll
  for (int g = 0; g < 4; ++g)
#pragma unroll
    for (int r = 0; r < 4; ++r)
      pfr[g][r] = Pb[((size_t)r * kCT + 0) * kG + (g << 8)];

  for (int tt = 0; tt < kCT; ++tt) {
    // acc <- prefetched P (C-operand), then issue next step's prefetch.
    f32x4 acc[4];
#pragma unroll
    for (int g = 0; g < 4; ++g) acc[g] = pfr[g];
    const int tn = (tt + 1 < kCT) ? (tt + 1) : tt;
#pragma unroll
    for (int g = 0; g < 4; ++g)
#pragma unroll
      for (int r = 0; r < 4; ++r)
        pfr[g][r] = Pb[((size_t)r * kCT + tn) * kG + (g << 8)];

    // A fragments: h for all 16 rows, conflict-free (lane reads own 16B).
    const unsigned short* ab = abuf[tt & 1];
    bf16x8 afr[8];
#pragma unroll
    for (int kb = 0; kb < 8; ++kb)
      afr[kb] = *reinterpret_cast<const bf16x8*>(ab + kb * 512 + l * 8);

    // gates[16 x 64-col slice] += h @ W^T  (4 gate-chains x 8 k-steps)
#pragma unroll
    for (int kb = 0; kb < 8; ++kb)
#pragma unroll
      for (int g = 0; g < 4; ++g)
        acc[g] = __builtin_amdgcn_mfma_f32_16x16x32_bf16(afr[kb], bfr[g][kb], acc[g], 0, 0, 0);

    // In-lane activation: lane holds i,f,g,o for (rows mg..mg+3, unit jj).
#pragma unroll
    for (int r = 0; r < 4; ++r) {
      const float ig = sigm(acc[0][r]);
      const float fg = sigm(acc[1][r]);
      const float gg = tanh_f(acc[2][r]);
      const float og = sigm(acc[3][r]);
      const float cc = fg * c4[r] + ig * gg;
      c4[r] = cc;
      hnew[r] = og * tanh_f(cc);
    }
    if (Hout) {
#pragma unroll
      for (int r = 0; r < 4; ++r)
        Hout[((size_t)(b0 + mg + r) * kCT + tt) * kH + jj] = hnew[r];
    }
    // Publish new h (bf16) into the other buffer, fragment order.
    {
      unsigned short* an = abuf[(tt + 1) & 1];
      const int kb_w = jj >> 5, hi = (jj >> 3) & 3, e = jj & 7;
#pragma unroll
      for (int r = 0; r < 4; ++r)
        an[kb_w * 512 + ((mg + r) | (hi << 4)) * 8 + e] = f2bf(hnew[r]);
    }
    __syncthreads();
  }

#pragma unroll
  for (int r = 0; r < 4; ++r) {
    hstate[(b0 + mg + r) * kH + jj] = hnew[r];
    cstate[(b0 + mg + r) * kH + jj] = c4[r];
  }
}

// ---------------------------------------------------------------------------
// P[m][n] = sum_k X[xrow(m)][k] * W[n][k] + b1[n] + b2[n]   (fp32, unchanged)
template <int K>
__global__ __launch_bounds__(256) void gemm_xw(
    const float* __restrict__ X, const float* __restrict__ W,
    const float* __restrict__ b1, const float* __restrict__ b2,
    float* __restrict__ P, int t0, int xT) {
  __shared__ float sA[64][20];
  __shared__ float sB[64][20];
  const int tid = threadIdx.x;
  const int tx = tid & 15;
  const int ty = tid >> 4;
  const int lm = tid >> 2;
  const int lk = (tid & 3) << 2;
  const int mt = blockIdx.y;
  const int nt = blockIdx.x;

  const int m_g = mt * 64 + lm;
  const int xrow = (m_g >> 6) * xT + t0 + (m_g & 63);
  const float* Arow = X + (size_t)xrow * K;
  const float* Brow = W + (size_t)(nt * 64 + lm) * K;

  float acc[4][4] = {};
  for (int kt = 0; kt < K; kt += 16) {
    const float4 av = *reinterpret_cast<const float4*>(Arow + kt + lk);
    const float4 bv = *reinterpret_cast<const float4*>(Brow + kt + lk);
    __syncthreads();
    *reinterpret_cast<float4*>(&sA[lm][lk]) = av;
    *reinterpret_cast<float4*>(&sB[lm][lk]) = bv;
    __syncthreads();
#pragma unroll
    for (int kq = 0; kq < 4; ++kq) {
      float4 a4[4], b4[4];
#pragma unroll
      for (int i = 0; i < 4; ++i)
        a4[i] = *reinterpret_cast<const float4*>(&sA[ty + 16 * i][kq * 4]);
#pragma unroll
      for (int j = 0; j < 4; ++j)
        b4[j] = *reinterpret_cast<const float4*>(&sB[tx + 16 * j][kq * 4]);
#pragma unroll
      for (int i = 0; i < 4; ++i)
#pragma unroll
        for (int j = 0; j < 4; ++j) {
          acc[i][j] += a4[i].x * b4[j].x;
          acc[i][j] += a4[i].y * b4[j].y;
          acc[i][j] += a4[i].z * b4[j].z;
          acc[i][j] += a4[i].w * b4[j].w;
        }
    }
  }
#pragma unroll
  for (int j = 0; j < 4; ++j) {
    const int n = nt * 64 + tx + 16 * j;
    const float bb = b1[n] + b2[n];
#pragma unroll
    for (int i = 0; i < 4; ++i) {
      const int m = mt * 64 + ty + 16 * i;
      P[(size_t)m * kG + n] = acc[i][j] + bb;
    }
  }
}

// out[b][n] = sum_k hlast[b][k] * fcw[n][k] + fcb[n]
__global__ __launch_bounds__(128) void fc_kernel(
    const float* __restrict__ hlast, const float* __restrict__ fcw,
    const float* __restrict__ fcb, float* __restrict__ out) {
  const int b = blockIdx.x;
  const int n = threadIdx.x;
  __shared__ float sh[kH];
  sh[n] = hlast[b * kH + n];
  sh[n + 128] = hlast[b * kH + n + 128];
  __syncthreads();
  if (n < kNC) {
    float a = fcb[n];
    const float* wrow = fcw + n * kH;
#pragma unroll 8
    for (int k = 0; k < kH; ++k) a += sh[k] * wrow[k];
    out[b * kNC + n] = a;
  }
}

}  // namespace

extern "C" void kernel_launch(void* const* d_in, const int* in_sizes, int n_in,
                              void* d_out, int out_size, void* d_ws, size_t ws_size,
                              hipStream_t stream) {
  (void)in_sizes; (void)n_in; (void)out_size; (void)ws_size;
  const float* x    = (const float*)d_in[0];
  const float* Wih0 = (const float*)d_in[1];
  const float* Whh0 = (const float*)d_in[2];
  const float* bih0 = (const float*)d_in[3];
  const float* bhh0 = (const float*)d_in[4];
  const float* Wih1 = (const float*)d_in[5];
  const float* Whh1 = (const float*)d_in[6];
  const float* bih1 = (const float*)d_in[7];
  const float* bhh1 = (const float*)d_in[8];
  const float* fcw  = (const float*)d_in[9];
  const float* fcb  = (const float*)d_in[10];
  float* out = (float*)d_out;

  // Workspace layout (~146 MB)
  char* base = (char*)d_ws;
  const size_t szP = (size_t)kB * kCT * kG * sizeof(float);  // 64 MB
  const size_t szH = (size_t)kB * kCT * kH * sizeof(float);  // 16 MB
  const size_t szS = (size_t)kB * kH * sizeof(float);        // 256 KB
  const size_t szW = (size_t)262144 * sizeof(unsigned short);// 512 KB
  float* P0  = (float*)(base);
  float* P1  = (float*)(base + szP);
  float* H0  = (float*)(base + 2 * szP);
  float* h0s = (float*)(base + 2 * szP + szH);
  float* c0s = (float*)(base + 2 * szP + szH + 1 * szS);
  float* h1s = (float*)(base + 2 * szP + szH + 2 * szS);
  float* c1s = (float*)(base + 2 * szP + szH + 3 * szS);
  unsigned short* Wpk0 = (unsigned short*)(base + 2 * szP + szH + 4 * szS);
  unsigned short* Wpk1 = (unsigned short*)(base + 2 * szP + szH + 4 * szS + szW);

  pack_whh_frag<<<dim3(1024), dim3(256), 0, stream>>>(Whh0, Wpk0);
  pack_whh_frag<<<dim3(1024), dim3(256), 0, stream>>>(Whh1, Wpk1);

  const dim3 ggrid(kG / 64, kB * kCT / 64);  // (16, 256)
  for (int ch = 0; ch < kNCh; ++ch) {
    const int first = (ch == 0) ? 1 : 0;
    gemm_xw<kIn><<<ggrid, dim3(256), 0, stream>>>(x, Wih0, bih0, bhh0, P0,
                                                  ch * kCT, kT);
    lstm_rec_mfma<<<dim3(kB / 16), dim3(1024), 0, stream>>>(P0, Wpk0, h0s, c0s,
                                                            H0, first);
    gemm_xw<kH><<<ggrid, dim3(256), 0, stream>>>(H0, Wih1, bih1, bhh1, P1,
                                                 0, kCT);
    lstm_rec_mfma<<<dim3(kB / 16), dim3(1024), 0, stream>>>(P1, Wpk1, h1s, c1s,
                                                            nullptr, first);
  }
  fc_kernel<<<dim3(kB), dim3(128), 0, stream>>>(h1s, fcw, fcb, out);
}